// Round 1
// baseline (3596.988 us; speedup 1.0000x reference)
//
#include <hip/hip_runtime.h>
#include <cstdint>
#include <cstddef>

// Problem constants
#define H_DIM   1024
#define T_STEPS 512           // L*N = 64*8 flattened time-major
#define VOCAB   32000
#define SENTU   0x40000000u   // 2.0f — unreachable: h = o*tanh(c) in [-1,1]
#define SPIN_CAP 5000000      // hang guard

__device__ __forceinline__ float gaload(const float* p) {
  return __hip_atomic_load(const_cast<float*>(p), __ATOMIC_RELAXED, __HIP_MEMORY_SCOPE_AGENT);
}
__device__ __forceinline__ void gastore(float* p, float v) {
  __hip_atomic_store(p, v, __ATOMIC_RELAXED, __HIP_MEMORY_SCOPE_AGENT);
}
__device__ __forceinline__ float sigmoid_f(float v) { return 1.f / (1.f + expf(-v)); }

// ---------------------------------------------------------------------------
// init: h0h/h1h slot 0 = zeros (initial state), slots 1..512 = sentinel.
// xmap[t] = x[n,l] time-major gather map.
// ---------------------------------------------------------------------------
__global__ void init_ws_k(const int* __restrict__ x,
                          float* __restrict__ h0h, float* __restrict__ h1h,
                          int* __restrict__ xmap)
{
  int tid = blockIdx.x * blockDim.x + threadIdx.x;
  int nt  = gridDim.x * blockDim.x;
  const float sent = __uint_as_float(SENTU);
  for (int i = tid; i < (T_STEPS + 1) * H_DIM; i += nt) {
    float v = (i < H_DIM) ? 0.f : sent;
    h0h[i] = v; h1h[i] = v;
  }
  for (int t = tid; t < T_STEPS; t += nt) xmap[t] = x[(t & 7) * 64 + (t >> 3)];
}

// ---------------------------------------------------------------------------
// fp32 GEMM  C[M,N] = A[M,K] @ B[N,K]^T + bias0 + bias1.
// If A==null, row t of A is gathered as emb[xmap[t]].
// 128x128 tile, BK=16, 256 threads, 8x8 per-thread microtile.  (unchanged)
// ---------------------------------------------------------------------------
#define BM 128
#define BN 128
#define BKD 16

__global__ __launch_bounds__(256) void gemm_atb_k(
    const float* __restrict__ A, const float* __restrict__ emb,
    const int* __restrict__ xmap,
    const float* __restrict__ B,
    const float* __restrict__ bias0, const float* __restrict__ bias1,
    float* __restrict__ C, int M, int N, int K)
{
  __shared__ __align__(16) float As[BKD][BM + 4];
  __shared__ __align__(16) float Bs[BKD][BN + 4];
  const int tid = threadIdx.x;
  const int tx = tid & 15, ty = tid >> 4;
  const int m0 = blockIdx.y * BM, n0 = blockIdx.x * BN;
  const int lr = tid >> 1;           // 0..127: row within tile
  const int lk = (tid & 1) * 8;      // 0 or 8: k sub-chunk
  const float* arow = A ? (A + (size_t)(m0 + lr) * K)
                        : (emb + (size_t)xmap[m0 + lr] * K);
  const float* brow = B + (size_t)(n0 + lr) * K;

  float acc[8][8];
  #pragma unroll
  for (int i = 0; i < 8; ++i)
    #pragma unroll
    for (int j = 0; j < 8; ++j) acc[i][j] = 0.f;

  for (int k0 = 0; k0 < K; k0 += BKD) {
    float4 a0 = *(const float4*)(arow + k0 + lk);
    float4 a1 = *(const float4*)(arow + k0 + lk + 4);
    float4 b0 = *(const float4*)(brow + k0 + lk);
    float4 b1 = *(const float4*)(brow + k0 + lk + 4);
    __syncthreads();   // protect previous iteration's LDS reads
    As[lk+0][lr]=a0.x; As[lk+1][lr]=a0.y; As[lk+2][lr]=a0.z; As[lk+3][lr]=a0.w;
    As[lk+4][lr]=a1.x; As[lk+5][lr]=a1.y; As[lk+6][lr]=a1.z; As[lk+7][lr]=a1.w;
    Bs[lk+0][lr]=b0.x; Bs[lk+1][lr]=b0.y; Bs[lk+2][lr]=b0.z; Bs[lk+3][lr]=b0.w;
    Bs[lk+4][lr]=b1.x; Bs[lk+5][lr]=b1.y; Bs[lk+6][lr]=b1.z; Bs[lk+7][lr]=b1.w;
    __syncthreads();
    #pragma unroll
    for (int kk = 0; kk < BKD; ++kk) {
      float4 av0 = *(const float4*)&As[kk][ty*8];
      float4 av1 = *(const float4*)&As[kk][ty*8+4];
      float4 bv0 = *(const float4*)&Bs[kk][tx*8];
      float4 bv1 = *(const float4*)&Bs[kk][tx*8+4];
      float av[8] = {av0.x,av0.y,av0.z,av0.w,av1.x,av1.y,av1.z,av1.w};
      float bv[8] = {bv0.x,bv0.y,bv0.z,bv0.w,bv1.x,bv1.y,bv1.z,bv1.w};
      #pragma unroll
      for (int i = 0; i < 8; ++i)
        #pragma unroll
        for (int j = 0; j < 8; ++j) acc[i][j] += av[i] * bv[j];
    }
  }
  float bvp[8];
  #pragma unroll
  for (int j = 0; j < 8; ++j) {
    int n = n0 + tx*8 + j;
    float s = 0.f;
    if (bias0) s += bias0[n];
    if (bias1) s += bias1[n];
    bvp[j] = s;
  }
  #pragma unroll
  for (int i = 0; i < 8; ++i) {
    int m = m0 + ty*8 + i;
    float* crow = C + (size_t)m * N + n0 + tx*8;
    float4 o0, o1;
    o0.x=acc[i][0]+bvp[0]; o0.y=acc[i][1]+bvp[1]; o0.z=acc[i][2]+bvp[2]; o0.w=acc[i][3]+bvp[3];
    o1.x=acc[i][4]+bvp[4]; o1.y=acc[i][5]+bvp[5]; o1.z=acc[i][6]+bvp[6]; o1.w=acc[i][7]+bvp[7];
    *(float4*)crow = o0;
    *(float4*)(crow + 4) = o1;
  }
}

// ---------------------------------------------------------------------------
// Persistent sequential LSTM scan — wave-autonomous gate ownership (round 4).
//
// 256 blocks x 512 threads. Blocks 0..127: layer 0. Blocks 128..255: layer 1
// (lags one step). Block owns hidden units [8b, 8b+8); WAVE w owns unit
// j = 8b + w with ALL FOUR gates:
//   L0: wr[4][16] = 64 weight VGPR/thread (4 gates x 1024 k / 64 lanes)
//   L1: wr[4][32] = 128 weight VGPR/thread (4 gates x 2048 k / 64 lanes)
// After the in-wave shfl reduce, lane 0 holds all 4 gate sums and computes
// sigmoid/tanh + c/h update IN-REGISTER, then stores h directly.
// vs round 3: eliminates barrier #2, the gbuf LDS round-trip, and the serial
// tid<8 phase from the per-step critical chain. hbuf is double-buffered so a
// SINGLE __syncthreads per step is race-free (a stager is at most one
// iteration ahead of any reader and writes the opposite parity buffer).
//
// VGPR ~190 (L1 branch dominates unified allocation) -> 1 block/CU; 256
// blocks on 256 CUs keeps full co-residency for the spin-sync.
//
// Sync = sentinel-in-data (round 3, correctness-proven): h histories
// pre-filled with 2.0f (h in [-1,1] can't produce it); consumers poll the
// data words directly. Hot-spin 16 iters then s_sleep(1) to limit poll
// traffic.
// ---------------------------------------------------------------------------
__global__ __launch_bounds__(512, 2) void lstm_seq_k(
    const float* __restrict__ Whh0,
    const float* __restrict__ Wih1,
    const float* __restrict__ Whh1,
    const float* __restrict__ bih1,
    const float* __restrict__ bhh1,
    const float* __restrict__ G0,
    float* __restrict__ h0h, float* __restrict__ h1h,   // (T+1) x 1024, sentinel
    float* __restrict__ h1out,                          // (512,1024) FC input
    float* __restrict__ out_hc)                         // h(2x1024) then c(2x1024)
{
  const int layer = blockIdx.x >> 7;
  const int b     = blockIdx.x & 127;
  const int jbase = b * 8;
  const int tid   = threadIdx.x;
  const int w     = tid >> 6;      // wave 0..7 — owns unit j
  const int lane  = tid & 63;
  const int j     = jbase + w;

  __shared__ __align__(16) float hbuf[2][2048];   // double-buffered staging

  if (layer == 0) {
    // ---- L0: K=1024; wave owns j, 4 gates; k slice = q*256 + lane*4 ----
    float wr[4][16];
    #pragma unroll
    for (int g = 0; g < 4; ++g) {
      const float* p = Whh0 + (size_t)(g*1024 + j) * 1024 + lane*4;
      #pragma unroll
      for (int q = 0; q < 4; ++q) {
        float4 v = *(const float4*)(p + q*256);
        wr[g][q*4+0]=v.x; wr[g][q*4+1]=v.y; wr[g][q*4+2]=v.z; wr[g][q*4+3]=v.w;
      }
    }
    float cst = 0.f;                 // lane 0's c for unit j
    for (int t = 0; t < T_STEPS; ++t) {
      float* hb = hbuf[t & 1];
      // G0 prefetch (independent of poll; only lane 0 needs it)
      float g0v[4] = {0.f,0.f,0.f,0.f};
      if (lane == 0) {
        const float* g0 = G0 + (size_t)t*4096 + j;
        #pragma unroll
        for (int q = 0; q < 4; ++q) g0v[q] = g0[q*1024];
      }
      if (tid < 256) {        // poll+stage h0h[t]: data IS the flag
        const float* p = h0h + (size_t)t * H_DIM + tid*4;
        float4 v; int sp = 0;
        for (;;) {
          v.x = gaload(p+0); v.y = gaload(p+1); v.z = gaload(p+2); v.w = gaload(p+3);
          if (__float_as_uint(v.x) != SENTU && __float_as_uint(v.y) != SENTU &&
              __float_as_uint(v.z) != SENTU && __float_as_uint(v.w) != SENTU) break;
          if (++sp > 16) __builtin_amdgcn_s_sleep(1);
          if (sp > SPIN_CAP) break;
        }
        *(float4*)&hb[tid*4] = v;
      }
      __syncthreads();
      float acc[4];
      {
        float4 xv[4];
        #pragma unroll
        for (int q = 0; q < 4; ++q) xv[q] = *(const float4*)&hb[q*256 + lane*4];
        #pragma unroll
        for (int g = 0; g < 4; ++g) {
          float s = 0.f;
          #pragma unroll
          for (int q = 0; q < 4; ++q)
            s += wr[g][q*4+0]*xv[q].x + wr[g][q*4+1]*xv[q].y +
                 wr[g][q*4+2]*xv[q].z + wr[g][q*4+3]*xv[q].w;
          acc[g] = s;
        }
      }
      #pragma unroll
      for (int msk = 1; msk < 64; msk <<= 1) {
        #pragma unroll
        for (int g = 0; g < 4; ++g) acc[g] += __shfl_xor(acc[g], msk, 64);
      }
      if (lane == 0) {
        float iv = sigmoid_f(acc[0] + g0v[0]);
        float fv = sigmoid_f(acc[1] + g0v[1]);
        float gv = tanhf   (acc[2] + g0v[2]);
        float ov = sigmoid_f(acc[3] + g0v[3]);
        float c  = fv * cst + iv * gv;
        cst = c;
        float h  = ov * tanhf(c);
        gastore(&h0h[(size_t)(t+1)*H_DIM + j], h);
        if (t == T_STEPS - 1) { out_hc[j] = h; out_hc[2048 + j] = c; }
      }
    }
  } else {
    // ---- L1: K=2048 concat [y[t]; h1[t-1]]; wave owns j, 4 gates ----
    float wr[4][32];
    #pragma unroll
    for (int g = 0; g < 4; ++g) {
      #pragma unroll
      for (int q = 0; q < 8; ++q) {
        const float* base = (q < 4) ? Wih1 : Whh1;
        const float* p = base + (size_t)(g*1024 + j) * 1024 + (q & 3)*256 + lane*4;
        float4 v = *(const float4*)p;
        wr[g][q*4+0]=v.x; wr[g][q*4+1]=v.y; wr[g][q*4+2]=v.z; wr[g][q*4+3]=v.w;
      }
    }
    float bi1[4] = {0.f,0.f,0.f,0.f};
    if (lane == 0) {
      #pragma unroll
      for (int q = 0; q < 4; ++q) bi1[q] = bih1[q*1024 + j] + bhh1[q*1024 + j];
    }
    float cst = 0.f;
    for (int t = 0; t < T_STEPS; ++t) {
      float* hb = hbuf[t & 1];
      { // poll+stage [h0h[t+1] ; h1h[t]] — 512 threads x 4 words
        const float* p = (tid < 256) ? (h0h + (size_t)(t+1)*H_DIM + tid*4)
                                     : (h1h + (size_t)t*H_DIM + (tid-256)*4);
        float4 v; int sp = 0;
        for (;;) {
          v.x = gaload(p+0); v.y = gaload(p+1); v.z = gaload(p+2); v.w = gaload(p+3);
          if (__float_as_uint(v.x) != SENTU && __float_as_uint(v.y) != SENTU &&
              __float_as_uint(v.z) != SENTU && __float_as_uint(v.w) != SENTU) break;
          if (++sp > 16) __builtin_amdgcn_s_sleep(1);
          if (sp > SPIN_CAP) break;
        }
        *(float4*)&hb[tid*4] = v;
      }
      __syncthreads();
      float acc[4];
      {
        float4 xv[8];
        #pragma unroll
        for (int q = 0; q < 8; ++q) xv[q] = *(const float4*)&hb[q*256 + lane*4];
        #pragma unroll
        for (int g = 0; g < 4; ++g) {
          float s = 0.f;
          #pragma unroll
          for (int q = 0; q < 8; ++q)
            s += wr[g][q*4+0]*xv[q].x + wr[g][q*4+1]*xv[q].y +
                 wr[g][q*4+2]*xv[q].z + wr[g][q*4+3]*xv[q].w;
          acc[g] = s;
        }
      }
      #pragma unroll
      for (int msk = 1; msk < 64; msk <<= 1) {
        #pragma unroll
        for (int g = 0; g < 4; ++g) acc[g] += __shfl_xor(acc[g], msk, 64);
      }
      if (lane == 0) {
        float iv = sigmoid_f(acc[0] + bi1[0]);
        float fv = sigmoid_f(acc[1] + bi1[1]);
        float gv = tanhf   (acc[2] + bi1[2]);
        float ov = sigmoid_f(acc[3] + bi1[3]);
        float c  = fv * cst + iv * gv;
        cst = c;
        float h  = ov * tanhf(c);
        gastore(&h1h[(size_t)(t+1)*H_DIM + j], h);
        h1out[(size_t)t*H_DIM + j] = h;
        if (t == T_STEPS - 1) { out_hc[1024 + j] = h; out_hc[3072 + j] = c; }
      }
    }
  }
}

// ---------------------------------------------------------------------------
extern "C" void kernel_launch(void* const* d_in, const int* in_sizes, int n_in,
                              void* d_out, int out_size, void* d_ws, size_t ws_size,
                              hipStream_t stream)
{
  (void)in_sizes; (void)n_in; (void)out_size; (void)ws_size;
  const int*   x    = (const int*)  d_in[0];
  const float* emb  = (const float*)d_in[1];
  const float* W_ih = (const float*)d_in[2];   // (2, 4096, 1024)
  const float* W_hh = (const float*)d_in[3];
  const float* b_ih = (const float*)d_in[4];   // (2, 4096)
  const float* b_hh = (const float*)d_in[5];
  const float* W_fc = (const float*)d_in[6];   // (32000, 1024)
  const float* b_fc = (const float*)d_in[7];
  float* out = (float*)d_out;                  // scores(512x32000) | h(2x1024) | c(2x1024)

  // workspace layout (floats); ~14.5 MB total
  float* ws    = (float*)d_ws;
  float* G0    = ws;                                         // 512*4096
  float* h0h   = G0   + (size_t)T_STEPS * 4096;              // 513*1024
  float* h1h   = h0h  + (size_t)(T_STEPS + 1) * H_DIM;       // 513*1024
  float* h1out = h1h  + (size_t)(T_STEPS + 1) * H_DIM;       // 512*1024
  int*   xmap  = (int*)(h1out + (size_t)T_STEPS * H_DIM);    // 512 ints

  init_ws_k<<<128, 256, 0, stream>>>(x, h0h, h1h, xmap);

  // G0[t,:] = W_ih0 @ emb[x_t] + b_ih0 + b_hh0   (512 x 4096)
  gemm_atb_k<<<dim3(4096 / BN, T_STEPS / BM), 256, 0, stream>>>(
      nullptr, emb, xmap, W_ih, b_ih, b_hh, G0, T_STEPS, 4096, 1024);

  // sequential scan (two layer domains, sentinel signaling, wave-autonomous)
  lstm_seq_k<<<256, 512, 0, stream>>>(
      W_hh, W_ih + (size_t)4096 * 1024, W_hh + (size_t)4096 * 1024,
      b_ih + 4096, b_hh + 4096, G0, h0h, h1h, h1out,
      out + (size_t)T_STEPS * VOCAB);

  // scores = outs @ W_fc^T + b_fc
  gemm_atb_k<<<dim3(VOCAB / BN, T_STEPS / BM), 256, 0, stream>>>(
      h1out, nullptr, nullptr, W_fc, b_fc, nullptr, out, T_STEPS, VOCAB, 1024);
}

// Round 2
// 2279.396 us; speedup vs baseline: 1.5780x; 1.5780x over previous
//
#include <hip/hip_runtime.h>
#include <cstdint>
#include <cstddef>

// Problem constants
#define H_DIM   1024
#define T_STEPS 512           // L*N = 64*8 flattened time-major
#define VOCAB   32000
#define SENTU   0x40000000u   // 2.0f — unreachable: h = o*tanh(c) in [-1,1]
#define SPIN_CAP 5000000      // hang guard

typedef unsigned int  uint_t;
typedef unsigned short ushort_t;

__device__ __forceinline__ float gaload(const float* p) {
  return __hip_atomic_load(const_cast<float*>(p), __ATOMIC_RELAXED, __HIP_MEMORY_SCOPE_AGENT);
}
__device__ __forceinline__ void gastore(float* p, float v) {
  __hip_atomic_store(p, v, __ATOMIC_RELAXED, __HIP_MEMORY_SCOPE_AGENT);
}
__device__ __forceinline__ float sigmoid_f(float v) { return 1.f / (1.f + expf(-v)); }

// fp32 -> bf16 (RNE) and two-term split: x ~= hi + lo, |err| ~ 2^-17 |x|
__device__ __forceinline__ ushort_t bf_rne(float x) {
  uint_t u = __float_as_uint(x);
  return (ushort_t)((u + 0x7FFFu + ((u >> 16) & 1u)) >> 16);
}
__device__ __forceinline__ void split2(float x, ushort_t& h, ushort_t& l) {
  h = bf_rne(x);
  float hf = __uint_as_float(((uint_t)h) << 16);
  l = bf_rne(x - hf);
}

// ---------------------------------------------------------------------------
// init: h0h/h1h slot 0 = zeros (initial state), slots 1..512 = sentinel.
// xmap[t] = x[n,l] time-major gather map.
// ---------------------------------------------------------------------------
__global__ void init_ws_k(const int* __restrict__ x,
                          float* __restrict__ h0h, float* __restrict__ h1h,
                          int* __restrict__ xmap)
{
  int tid = blockIdx.x * blockDim.x + threadIdx.x;
  int nt  = gridDim.x * blockDim.x;
  const float sent = __uint_as_float(SENTU);
  for (int i = tid; i < (T_STEPS + 1) * H_DIM; i += nt) {
    float v = (i < H_DIM) ? 0.f : sent;
    h0h[i] = v; h1h[i] = v;
  }
  for (int t = tid; t < T_STEPS; t += nt) xmap[t] = x[(t & 7) * 64 + (t >> 3)];
}

// ---------------------------------------------------------------------------
// fp32 GEMM  C[M,N] = A[M,K] @ B[N,K]^T + bias0 + bias1.  (used for G0 only)
// If A==null, row t of A is gathered as emb[xmap[t]].
// 128x128 tile, BK=16, 256 threads, 8x8 per-thread microtile.
// ---------------------------------------------------------------------------
#define BM 128
#define BN 128
#define BKD 16

__global__ __launch_bounds__(256) void gemm_atb_k(
    const float* __restrict__ A, const float* __restrict__ emb,
    const int* __restrict__ xmap,
    const float* __restrict__ B,
    const float* __restrict__ bias0, const float* __restrict__ bias1,
    float* __restrict__ C, int M, int N, int K)
{
  __shared__ __align__(16) float As[BKD][BM + 4];
  __shared__ __align__(16) float Bs[BKD][BN + 4];
  const int tid = threadIdx.x;
  const int tx = tid & 15, ty = tid >> 4;
  const int m0 = blockIdx.y * BM, n0 = blockIdx.x * BN;
  const int lr = tid >> 1;           // 0..127: row within tile
  const int lk = (tid & 1) * 8;      // 0 or 8: k sub-chunk
  const float* arow = A ? (A + (size_t)(m0 + lr) * K)
                        : (emb + (size_t)xmap[m0 + lr] * K);
  const float* brow = B + (size_t)(n0 + lr) * K;

  float acc[8][8];
  #pragma unroll
  for (int i = 0; i < 8; ++i)
    #pragma unroll
    for (int j = 0; j < 8; ++j) acc[i][j] = 0.f;

  for (int k0 = 0; k0 < K; k0 += BKD) {
    float4 a0 = *(const float4*)(arow + k0 + lk);
    float4 a1 = *(const float4*)(arow + k0 + lk + 4);
    float4 b0 = *(const float4*)(brow + k0 + lk);
    float4 b1 = *(const float4*)(brow + k0 + lk + 4);
    __syncthreads();   // protect previous iteration's LDS reads
    As[lk+0][lr]=a0.x; As[lk+1][lr]=a0.y; As[lk+2][lr]=a0.z; As[lk+3][lr]=a0.w;
    As[lk+4][lr]=a1.x; As[lk+5][lr]=a1.y; As[lk+6][lr]=a1.z; As[lk+7][lr]=a1.w;
    Bs[lk+0][lr]=b0.x; Bs[lk+1][lr]=b0.y; Bs[lk+2][lr]=b0.z; Bs[lk+3][lr]=b0.w;
    Bs[lk+4][lr]=b1.x; Bs[lk+5][lr]=b1.y; Bs[lk+6][lr]=b1.z; Bs[lk+7][lr]=b1.w;
    __syncthreads();
    #pragma unroll
    for (int kk = 0; kk < BKD; ++kk) {
      float4 av0 = *(const float4*)&As[kk][ty*8];
      float4 av1 = *(const float4*)&As[kk][ty*8+4];
      float4 bv0 = *(const float4*)&Bs[kk][tx*8];
      float4 bv1 = *(const float4*)&Bs[kk][tx*8+4];
      float av[8] = {av0.x,av0.y,av0.z,av0.w,av1.x,av1.y,av1.z,av1.w};
      float bv[8] = {bv0.x,bv0.y,bv0.z,bv0.w,bv1.x,bv1.y,bv1.z,bv1.w};
      #pragma unroll
      for (int i = 0; i < 8; ++i)
        #pragma unroll
        for (int j = 0; j < 8; ++j) acc[i][j] += av[i] * bv[j];
    }
  }
  float bvp[8];
  #pragma unroll
  for (int j = 0; j < 8; ++j) {
    int n = n0 + tx*8 + j;
    float s = 0.f;
    if (bias0) s += bias0[n];
    if (bias1) s += bias1[n];
    bvp[j] = s;
  }
  #pragma unroll
  for (int i = 0; i < 8; ++i) {
    int m = m0 + ty*8 + i;
    float* crow = C + (size_t)m * N + n0 + tx*8;
    float4 o0, o1;
    o0.x=acc[i][0]+bvp[0]; o0.y=acc[i][1]+bvp[1]; o0.z=acc[i][2]+bvp[2]; o0.w=acc[i][3]+bvp[3];
    o1.x=acc[i][4]+bvp[4]; o1.y=acc[i][5]+bvp[5]; o1.z=acc[i][6]+bvp[6]; o1.w=acc[i][7]+bvp[7];
    *(float4*)crow = o0;
    *(float4*)(crow + 4) = o1;
  }
}

// ---------------------------------------------------------------------------
// Persistent sequential LSTM scan — REVERTED to the round-3 proven structure
// (1805 us, no spill). Round-4 post-mortem: wave-autonomous remap (wr[4][32])
// made the allocator spill ~112 floats/thread to scratch (VGPR 104->96,
// WRITE_SIZE +28.7MB, +1100us). This layout (wr[8][8] L0 / wr[8][16] L1,
// AGPR-backed) is the known-good register-resident configuration.
//
// 256 blocks x 512 threads. Blocks 0..127: layer 0. Blocks 128..255: layer 1
// (lags one step). Block owns hidden units [8b, 8b+8) + their c. Wave w =
// (gate w>>1, K-half w&1). Sync = sentinel-in-data: h histories pre-filled
// with 2.0f (h in [-1,1] can't produce it); consumers poll data words
// directly. Hot-spin 16 iters then s_sleep(1).
// ---------------------------------------------------------------------------
__global__ __launch_bounds__(512, 2) void lstm_seq_k(
    const float* __restrict__ Whh0,
    const float* __restrict__ Wih1,
    const float* __restrict__ Whh1,
    const float* __restrict__ bih1,
    const float* __restrict__ bhh1,
    const float* __restrict__ G0,
    float* __restrict__ h0h, float* __restrict__ h1h,   // (T+1) x 1024, sentinel
    float* __restrict__ h1out,                          // (512,1024) FC input
    float* __restrict__ out_hc)                         // h(2x1024) then c(2x1024)
{
  const int layer = blockIdx.x >> 7;
  const int b     = blockIdx.x & 127;
  const int jbase = b * 8;
  const int tid   = threadIdx.x;
  const int w     = tid >> 6;      // 0..7
  const int g     = w >> 1;        // gate i,f,g,o
  const int hh    = w & 1;         // k-half
  const int lane  = tid & 63;

  __shared__ __align__(16) float hbuf[2048];
  __shared__ float gbuf[8][8];
  __shared__ float cbuf[8];
  if (tid < 8) cbuf[tid] = 0.f;

  if (layer == 0) {
    // ---- L0: K=1024; wave covers k in [hh*512, hh*512+512); 64 wVGPR ----
    float wr[8][8];
    #pragma unroll
    for (int j = 0; j < 8; ++j) {
      const float* p = Whh0 + (size_t)(g*1024 + jbase + j) * 1024 + hh*512 + lane*4;
      #pragma unroll
      for (int q = 0; q < 2; ++q) {
        float4 v = *(const float4*)(p + q*256);
        wr[j][q*4+0]=v.x; wr[j][q*4+1]=v.y; wr[j][q*4+2]=v.z; wr[j][q*4+3]=v.w;
      }
    }
    __syncthreads();
    for (int t = 0; t < T_STEPS; ++t) {
      // G0 prefetch (independent of poll)
      float g0v[4] = {0.f,0.f,0.f,0.f};
      if (tid < 8) {
        const float* g0 = G0 + (size_t)t*4096 + jbase + tid;
        #pragma unroll
        for (int q = 0; q < 4; ++q) g0v[q] = g0[q*1024];
      }
      if (tid < 256) {        // poll+stage h0h[t]: data IS the flag
        const float* p = h0h + (size_t)t * H_DIM + tid*4;
        float4 v; int sp = 0;
        for (;;) {
          v.x = gaload(p+0); v.y = gaload(p+1); v.z = gaload(p+2); v.w = gaload(p+3);
          if (__float_as_uint(v.x) != SENTU && __float_as_uint(v.y) != SENTU &&
              __float_as_uint(v.z) != SENTU && __float_as_uint(v.w) != SENTU) break;
          if (++sp > 16) __builtin_amdgcn_s_sleep(1);
          if (sp > SPIN_CAP) break;
        }
        *(float4*)&hbuf[tid*4] = v;
      }
      __syncthreads();
      float acc[8];
      {
        float4 xv0 = *(const float4*)&hbuf[hh*512 + lane*4];
        float4 xv1 = *(const float4*)&hbuf[hh*512 + 256 + lane*4];
        #pragma unroll
        for (int j = 0; j < 8; ++j)
          acc[j] = wr[j][0]*xv0.x + wr[j][1]*xv0.y + wr[j][2]*xv0.z + wr[j][3]*xv0.w +
                   wr[j][4]*xv1.x + wr[j][5]*xv1.y + wr[j][6]*xv1.z + wr[j][7]*xv1.w;
      }
      #pragma unroll
      for (int j = 0; j < 8; ++j)
        #pragma unroll
        for (int msk = 1; msk < 64; msk <<= 1)
          acc[j] += __shfl_xor(acc[j], msk, 64);
      if (lane == 0) {
        #pragma unroll
        for (int j = 0; j < 8; ++j) gbuf[w][j] = acc[j];
      }
      __syncthreads();
      if (tid < 8) {
        const int j = tid;
        float iv = sigmoid_f(gbuf[0][j] + gbuf[1][j] + g0v[0]);
        float fv = sigmoid_f(gbuf[2][j] + gbuf[3][j] + g0v[1]);
        float gv = tanhf   (gbuf[4][j] + gbuf[5][j] + g0v[2]);
        float ov = sigmoid_f(gbuf[6][j] + gbuf[7][j] + g0v[3]);
        float c  = fv * cbuf[j] + iv * gv;
        cbuf[j]  = c;
        float h  = ov * tanhf(c);
        gastore(&h0h[(size_t)(t+1)*H_DIM + jbase + j], h);
        if (t == T_STEPS - 1) { out_hc[jbase + j] = h; out_hc[2048 + jbase + j] = c; }
      }
    }
  } else {
    // ---- L1: K=2048 concat [y[t]; h1[t-1]]; wave covers 1024 k; 128 wVGPR ----
    float wr[8][16];
    {
      const float* base = hh ? Whh1 : Wih1;
      #pragma unroll
      for (int j = 0; j < 8; ++j) {
        const float* p = base + (size_t)(g*1024 + jbase + j) * 1024 + lane*4;
        #pragma unroll
        for (int q = 0; q < 4; ++q) {
          float4 v = *(const float4*)(p + q*256);
          wr[j][q*4+0]=v.x; wr[j][q*4+1]=v.y; wr[j][q*4+2]=v.z; wr[j][q*4+3]=v.w;
        }
      }
    }
    float bi1[4] = {0.f,0.f,0.f,0.f};
    if (tid < 8) {
      int j = jbase + tid;
      #pragma unroll
      for (int q = 0; q < 4; ++q) bi1[q] = bih1[q*1024 + j] + bhh1[q*1024 + j];
    }
    __syncthreads();
    for (int t = 0; t < T_STEPS; ++t) {
      { // poll+stage [h0h[t+1] ; h1h[t]] — 512 threads x 4 words
        const float* p = (tid < 256) ? (h0h + (size_t)(t+1)*H_DIM + tid*4)
                                     : (h1h + (size_t)t*H_DIM + (tid-256)*4);
        float4 v; int sp = 0;
        for (;;) {
          v.x = gaload(p+0); v.y = gaload(p+1); v.z = gaload(p+2); v.w = gaload(p+3);
          if (__float_as_uint(v.x) != SENTU && __float_as_uint(v.y) != SENTU &&
              __float_as_uint(v.z) != SENTU && __float_as_uint(v.w) != SENTU) break;
          if (++sp > 16) __builtin_amdgcn_s_sleep(1);
          if (sp > SPIN_CAP) break;
        }
        *(float4*)&hbuf[tid*4] = v;
      }
      __syncthreads();
      float acc[8];
      {
        float4 xv[4];
        #pragma unroll
        for (int q = 0; q < 4; ++q)
          xv[q] = *(const float4*)&hbuf[hh*1024 + q*256 + lane*4];
        #pragma unroll
        for (int j = 0; j < 8; ++j) {
          float s = 0.f;
          #pragma unroll
          for (int q = 0; q < 4; ++q)
            s += wr[j][q*4+0]*xv[q].x + wr[j][q*4+1]*xv[q].y +
                 wr[j][q*4+2]*xv[q].z + wr[j][q*4+3]*xv[q].w;
          acc[j] = s;
        }
      }
      #pragma unroll
      for (int j = 0; j < 8; ++j)
        #pragma unroll
        for (int msk = 1; msk < 64; msk <<= 1)
          acc[j] += __shfl_xor(acc[j], msk, 64);
      if (lane == 0) {
        #pragma unroll
        for (int j = 0; j < 8; ++j) gbuf[w][j] = acc[j];
      }
      __syncthreads();
      if (tid < 8) {
        const int j = tid;
        float iv = sigmoid_f(gbuf[0][j] + gbuf[1][j] + bi1[0]);
        float fv = sigmoid_f(gbuf[2][j] + gbuf[3][j] + bi1[1]);
        float gv = tanhf   (gbuf[4][j] + gbuf[5][j] + bi1[2]);
        float ov = sigmoid_f(gbuf[6][j] + gbuf[7][j] + bi1[3]);
        float c  = fv * cbuf[j] + iv * gv;
        cbuf[j]  = c;
        float h  = ov * tanhf(c);
        gastore(&h1h[(size_t)(t+1)*H_DIM + jbase + j], h);
        h1out[(size_t)t*H_DIM + jbase + j] = h;
        if (t == T_STEPS - 1) { out_hc[1024 + jbase + j] = h; out_hc[3072 + jbase + j] = c; }
      }
    }
  }
}

// ---------------------------------------------------------------------------
// split_a_k: h1out (512x1024 fp32) -> A_hi, A_lo (bf16 pair), row-major [m][k].
// ---------------------------------------------------------------------------
__global__ void split_a_k(const float* __restrict__ A,
                          ushort_t* __restrict__ Ahi, ushort_t* __restrict__ Alo)
{
  int i = (blockIdx.x * blockDim.x + threadIdx.x) * 4;
  if (i >= T_STEPS * H_DIM) return;
  float4 v = *(const float4*)(A + i);
  ushort4 h, l;
  split2(v.x, h.x, l.x); split2(v.y, h.y, l.y);
  split2(v.z, h.z, l.z); split2(v.w, h.w, l.w);
  *(ushort4*)(Ahi + i) = h;
  *(ushort4*)(Alo + i) = l;
}

// ---------------------------------------------------------------------------
// fc_mfma_k: scores = A @ W^T + b via split-bf16 (bf16x3) MFMA.
//   C[m][n] = sum_k (Ah+Al)[m][k] * (Wh+Wl)[n][k]
//           ~ Ah*Wh + Ah*Wl + Al*Wh   (Al*Wl term ~2^-18 rel, dropped)
// A pre-split (bf16); W split fp32->bf16 per-tile in-kernel (no big ws).
// Tile 256x128, BK=32, 512 threads = 8 waves (4M x 2N), wave tile 64x64 =
// 4x4 x mfma_f32_16x16x32_bf16. LDS rows padded to 40 bf16 (80 B): 16-lane
// frag reads land 2-way on banks (free, m136). Reg-staged loads for tile
// k+1 issued before compute of tile k (T14-lite).
// Fragment layout (guide §3, m89-verified): A/B lane reads row (lane&15),
// k0=(lane>>4)*8, 8 contiguous bf16; C/D col=lane&15, row=(lane>>4)*4+reg.
// ---------------------------------------------------------------------------
typedef __attribute__((ext_vector_type(8))) short bf16x8;
typedef __attribute__((ext_vector_type(4))) float f32x4;

#define FBM 256
#define FBN 128
#define FBK 32
#define FPITCH 40   // 32 + 8 pad, bf16 elements per LDS row

__global__ __launch_bounds__(512, 2) void fc_mfma_k(
    const ushort_t* __restrict__ Ahi, const ushort_t* __restrict__ Alo,
    const float* __restrict__ W,      // (32000,1024) fp32
    const float* __restrict__ bias,   // (32000)
    float* __restrict__ C)            // (512,32000)
{
  __shared__ __align__(16) ushort_t Ah[FBM * FPITCH];
  __shared__ __align__(16) ushort_t Al[FBM * FPITCH];
  __shared__ __align__(16) ushort_t Wh[FBN * FPITCH];
  __shared__ __align__(16) ushort_t Wl[FBN * FPITCH];

  const int tid  = threadIdx.x;
  const int m0   = blockIdx.y * FBM;
  const int n0   = blockIdx.x * FBN;
  const int wid  = tid >> 6, lane = tid & 63;
  const int wm   = wid & 3, wn = wid >> 2;        // wave tile (wm*64, wn*64)
  const int frow = lane & 15, fk = (lane >> 4) * 8;

  f32x4 acc[4][4] = {};   // acc[mt][nt]

  // staged-tile registers
  uint4 rah0, rah1, ral0, ral1;
  float4 rw0, rw1;

  auto LOADTILE = [&](int kt) {
    { int c = tid;       int r = c >> 2, kc = (c & 3) * 8;
      size_t off = (size_t)(m0 + r) * 1024 + kt * FBK + kc;
      rah0 = *(const uint4*)(Ahi + off);
      ral0 = *(const uint4*)(Alo + off); }
    { int c = tid + 512; int r = c >> 2, kc = (c & 3) * 8;
      size_t off = (size_t)(m0 + r) * 1024 + kt * FBK + kc;
      rah1 = *(const uint4*)(Ahi + off);
      ral1 = *(const uint4*)(Alo + off); }
    { int c = tid;       int r = c >> 3, kc = (c & 7) * 4;
      rw0 = *(const float4*)(W + (size_t)(n0 + r) * 1024 + kt * FBK + kc); }
    { int c = tid + 512; int r = c >> 3, kc = (c & 7) * 4;
      rw1 = *(const float4*)(W + (size_t)(n0 + r) * 1024 + kt * FBK + kc); }
  };
  auto STORETILE = [&]() {
    { int c = tid;       int r = c >> 2, kc = (c & 3) * 8;
      *(uint4*)&Ah[r * FPITCH + kc] = rah0;
      *(uint4*)&Al[r * FPITCH + kc] = ral0; }
    { int c = tid + 512; int r = c >> 2, kc = (c & 3) * 8;
      *(uint4*)&Ah[r * FPITCH + kc] = rah1;
      *(uint4*)&Al[r * FPITCH + kc] = ral1; }
    { int c = tid;       int r = c >> 3, kc = (c & 7) * 4;
      ushort4 h, l;
      split2(rw0.x, h.x, l.x); split2(rw0.y, h.y, l.y);
      split2(rw0.z, h.z, l.z); split2(rw0.w, h.w, l.w);
      *(ushort4*)&Wh[r * FPITCH + kc] = h;
      *(ushort4*)&Wl[r * FPITCH + kc] = l; }
    { int c = tid + 512; int r = c >> 3, kc = (c & 7) * 4;
      ushort4 h, l;
      split2(rw1.x, h.x, l.x); split2(rw1.y, h.y, l.y);
      split2(rw1.z, h.z, l.z); split2(rw1.w, h.w, l.w);
      *(ushort4*)&Wh[r * FPITCH + kc] = h;
      *(ushort4*)&Wl[r * FPITCH + kc] = l; }
  };

  LOADTILE(0);
  const int NK = 1024 / FBK;
  for (int kt = 0; kt < NK; ++kt) {
    __syncthreads();            // prev tile's LDS consumers done
    STORETILE();
    __syncthreads();
    if (kt + 1 < NK) LOADTILE(kt + 1);   // overlap next loads with compute

    bf16x8 bh[4], bl[4];
    #pragma unroll
    for (int nt = 0; nt < 4; ++nt) {
      int br = (wn * 64 + nt * 16 + frow) * FPITCH + fk;
      bh[nt] = *(const bf16x8*)&Wh[br];
      bl[nt] = *(const bf16x8*)&Wl[br];
    }
    #pragma unroll
    for (int mt = 0; mt < 4; ++mt) {
      int ar = (wm * 64 + mt * 16 + frow) * FPITCH + fk;
      bf16x8 ah = *(const bf16x8*)&Ah[ar];
      bf16x8 al = *(const bf16x8*)&Al[ar];
      #pragma unroll
      for (int nt = 0; nt < 4; ++nt) {
        acc[mt][nt] = __builtin_amdgcn_mfma_f32_16x16x32_bf16(ah, bh[nt], acc[mt][nt], 0, 0, 0);
        acc[mt][nt] = __builtin_amdgcn_mfma_f32_16x16x32_bf16(ah, bl[nt], acc[mt][nt], 0, 0, 0);
        acc[mt][nt] = __builtin_amdgcn_mfma_f32_16x16x32_bf16(al, bh[nt], acc[mt][nt], 0, 0, 0);
      }
    }
  }

  // epilogue: C/D map col=lane&15, row=(lane>>4)*4+reg
  #pragma unroll
  for (int nt = 0; nt < 4; ++nt) {
    int col = n0 + wn * 64 + nt * 16 + frow;
    float bv = bias[col];
    #pragma unroll
    for (int mt = 0; mt < 4; ++mt) {
      int rbase = m0 + wm * 64 + mt * 16 + (lane >> 4) * 4;
      #pragma unroll
      for (int r = 0; r < 4; ++r)
        C[(size_t)(rbase + r) * VOCAB + col] = acc[mt][nt][r] + bv;
    }
  }
}

// ---------------------------------------------------------------------------
extern "C" void kernel_launch(void* const* d_in, const int* in_sizes, int n_in,
                              void* d_out, int out_size, void* d_ws, size_t ws_size,
                              hipStream_t stream)
{
  (void)in_sizes; (void)n_in; (void)out_size; (void)ws_size;
  const int*   x    = (const int*)  d_in[0];
  const float* emb  = (const float*)d_in[1];
  const float* W_ih = (const float*)d_in[2];   // (2, 4096, 1024)
  const float* W_hh = (const float*)d_in[3];
  const float* b_ih = (const float*)d_in[4];   // (2, 4096)
  const float* b_hh = (const float*)d_in[5];
  const float* W_fc = (const float*)d_in[6];   // (32000, 1024)
  const float* b_fc = (const float*)d_in[7];
  float* out = (float*)d_out;                  // scores(512x32000) | h(2x1024) | c(2x1024)

  // workspace layout (floats); ~16.3 MB total
  float* ws    = (float*)d_ws;
  float* G0    = ws;                                         // 512*4096
  float* h0h   = G0   + (size_t)T_STEPS * 4096;              // 513*1024
  float* h1h   = h0h  + (size_t)(T_STEPS + 1) * H_DIM;       // 513*1024
  float* h1out = h1h  + (size_t)(T_STEPS + 1) * H_DIM;       // 512*1024
  int*   xmap  = (int*)(h1out + (size_t)T_STEPS * H_DIM);    // 512 ints
  ushort_t* Ahi = (ushort_t*)(xmap + 512);                   // 512*1024 bf16
  ushort_t* Alo = Ahi + (size_t)T_STEPS * H_DIM;             // 512*1024 bf16

  init_ws_k<<<128, 256, 0, stream>>>(x, h0h, h1h, xmap);

  // G0[t,:] = W_ih0 @ emb[x_t] + b_ih0 + b_hh0   (512 x 4096)
  gemm_atb_k<<<dim3(4096 / BN, T_STEPS / BM), 256, 0, stream>>>(
      nullptr, emb, xmap, W_ih, b_ih, b_hh, G0, T_STEPS, 4096, 1024);

  // sequential scan (two layer domains, sentinel signaling, no spill)
  lstm_seq_k<<<256, 512, 0, stream>>>(
      W_hh, W_ih + (size_t)4096 * 1024, W_hh + (size_t)4096 * 1024,
      b_ih + 4096, b_hh + 4096, G0, h0h, h1h, h1out,
      out + (size_t)T_STEPS * VOCAB);

  // split FC input to bf16 hi/lo
  split_a_k<<<(T_STEPS * H_DIM / 4 + 255) / 256, 256, 0, stream>>>(h1out, Ahi, Alo);

  // scores = outs @ W_fc^T + b_fc  (split-bf16 MFMA)
  fc_mfma_k<<<dim3(VOCAB / FBN, T_STEPS / FBM), 512, 0, stream>>>(
      Ahi, Alo, W_fc, b_fc, out);
}

// Round 3
// 2083.813 us; speedup vs baseline: 1.7262x; 1.0939x over previous
//
#include <hip/hip_runtime.h>
#include <cstdint>
#include <cstddef>

// Problem constants
#define H_DIM   1024
#define T_STEPS 512           // L*N = 64*8 flattened time-major
#define VOCAB   32000
#define SENTU   0x40000000u   // 2.0f — unreachable: h = o*tanh(c) in [-1,1]
#define SPIN_CAP 5000000      // hang guard

typedef unsigned int  uint_t;
typedef unsigned short ushort_t;
typedef float __attribute__((ext_vector_type(4))) f4_t;

__device__ __forceinline__ float gaload(const float* p) {
  return __hip_atomic_load(const_cast<float*>(p), __ATOMIC_RELAXED, __HIP_MEMORY_SCOPE_AGENT);
}
__device__ __forceinline__ void gastore(float* p, float v) {
  __hip_atomic_store(p, v, __ATOMIC_RELAXED, __HIP_MEMORY_SCOPE_AGENT);
}
// One 16B coherent load (bypasses non-coherent XCD L2 via sc0 sc1) replacing
// 4 dword agent-scope loads: 4x fewer L3 requests on the poll path. waitcnt
// fused in the same asm block so consumers can't be scheduled before data
// lands (rule: separate-asm waitcnt can be bypassed by non-asm uses).
__device__ __forceinline__ f4_t poll4(const float* p) {
  f4_t v;
  asm volatile("global_load_dwordx4 %0, %1, off sc0 sc1\n\ts_waitcnt vmcnt(0)"
               : "=v"(v) : "v"(p) : "memory");
  return v;
}
__device__ __forceinline__ float sigmoid_f(float v) { return 1.f / (1.f + expf(-v)); }

// fp32 -> bf16 (RNE) and two-term split: x ~= hi + lo, |err| ~ 2^-17 |x|
__device__ __forceinline__ ushort_t bf_rne(float x) {
  uint_t u = __float_as_uint(x);
  return (ushort_t)((u + 0x7FFFu + ((u >> 16) & 1u)) >> 16);
}
__device__ __forceinline__ void split2(float x, ushort_t& h, ushort_t& l) {
  h = bf_rne(x);
  float hf = __uint_as_float(((uint_t)h) << 16);
  l = bf_rne(x - hf);
}

// ---------------------------------------------------------------------------
// init: h0h/h1h slot 0 = zeros (initial state), slots 1..512 = sentinel.
// xmap[t] = x[n,l] time-major gather map.
// ---------------------------------------------------------------------------
__global__ void init_ws_k(const int* __restrict__ x,
                          float* __restrict__ h0h, float* __restrict__ h1h,
                          int* __restrict__ xmap)
{
  int tid = blockIdx.x * blockDim.x + threadIdx.x;
  int nt  = gridDim.x * blockDim.x;
  const float sent = __uint_as_float(SENTU);
  for (int i = tid; i < (T_STEPS + 1) * H_DIM; i += nt) {
    float v = (i < H_DIM) ? 0.f : sent;
    h0h[i] = v; h1h[i] = v;
  }
  for (int t = tid; t < T_STEPS; t += nt) xmap[t] = x[(t & 7) * 64 + (t >> 3)];
}

// ---------------------------------------------------------------------------
// fp32 GEMM  C[M,N] = A[M,K] @ B[N,K]^T + bias0 + bias1.  (used for G0 only)
// If A==null, row t of A is gathered as emb[xmap[t]].
// 128x128 tile, BK=16, 256 threads, 8x8 per-thread microtile.
// ---------------------------------------------------------------------------
#define BM 128
#define BN 128
#define BKD 16

__global__ __launch_bounds__(256) void gemm_atb_k(
    const float* __restrict__ A, const float* __restrict__ emb,
    const int* __restrict__ xmap,
    const float* __restrict__ B,
    const float* __restrict__ bias0, const float* __restrict__ bias1,
    float* __restrict__ C, int M, int N, int K)
{
  __shared__ __align__(16) float As[BKD][BM + 4];
  __shared__ __align__(16) float Bs[BKD][BN + 4];
  const int tid = threadIdx.x;
  const int tx = tid & 15, ty = tid >> 4;
  const int m0 = blockIdx.y * BM, n0 = blockIdx.x * BN;
  const int lr = tid >> 1;           // 0..127: row within tile
  const int lk = (tid & 1) * 8;      // 0 or 8: k sub-chunk
  const float* arow = A ? (A + (size_t)(m0 + lr) * K)
                        : (emb + (size_t)xmap[m0 + lr] * K);
  const float* brow = B + (size_t)(n0 + lr) * K;

  float acc[8][8];
  #pragma unroll
  for (int i = 0; i < 8; ++i)
    #pragma unroll
    for (int j = 0; j < 8; ++j) acc[i][j] = 0.f;

  for (int k0 = 0; k0 < K; k0 += BKD) {
    float4 a0 = *(const float4*)(arow + k0 + lk);
    float4 a1 = *(const float4*)(arow + k0 + lk + 4);
    float4 b0 = *(const float4*)(brow + k0 + lk);
    float4 b1 = *(const float4*)(brow + k0 + lk + 4);
    __syncthreads();   // protect previous iteration's LDS reads
    As[lk+0][lr]=a0.x; As[lk+1][lr]=a0.y; As[lk+2][lr]=a0.z; As[lk+3][lr]=a0.w;
    As[lk+4][lr]=a1.x; As[lk+5][lr]=a1.y; As[lk+6][lr]=a1.z; As[lk+7][lr]=a1.w;
    Bs[lk+0][lr]=b0.x; Bs[lk+1][lr]=b0.y; Bs[lk+2][lr]=b0.z; Bs[lk+3][lr]=b0.w;
    Bs[lk+4][lr]=b1.x; Bs[lk+5][lr]=b1.y; Bs[lk+6][lr]=b1.z; Bs[lk+7][lr]=b1.w;
    __syncthreads();
    #pragma unroll
    for (int kk = 0; kk < BKD; ++kk) {
      float4 av0 = *(const float4*)&As[kk][ty*8];
      float4 av1 = *(const float4*)&As[kk][ty*8+4];
      float4 bv0 = *(const float4*)&Bs[kk][tx*8];
      float4 bv1 = *(const float4*)&Bs[kk][tx*8+4];
      float av[8] = {av0.x,av0.y,av0.z,av0.w,av1.x,av1.y,av1.z,av1.w};
      float bv[8] = {bv0.x,bv0.y,bv0.z,bv0.w,bv1.x,bv1.y,bv1.z,bv1.w};
      #pragma unroll
      for (int i = 0; i < 8; ++i)
        #pragma unroll
        for (int j = 0; j < 8; ++j) acc[i][j] += av[i] * bv[j];
    }
  }
  float bvp[8];
  #pragma unroll
  for (int j = 0; j < 8; ++j) {
    int n = n0 + tx*8 + j;
    float s = 0.f;
    if (bias0) s += bias0[n];
    if (bias1) s += bias1[n];
    bvp[j] = s;
  }
  #pragma unroll
  for (int i = 0; i < 8; ++i) {
    int m = m0 + ty*8 + i;
    float* crow = C + (size_t)m * N + n0 + tx*8;
    float4 o0, o1;
    o0.x=acc[i][0]+bvp[0]; o0.y=acc[i][1]+bvp[1]; o0.z=acc[i][2]+bvp[2]; o0.w=acc[i][3]+bvp[3];
    o1.x=acc[i][4]+bvp[4]; o1.y=acc[i][5]+bvp[5]; o1.z=acc[i][6]+bvp[6]; o1.w=acc[i][7]+bvp[7];
    *(float4*)crow = o0;
    *(float4*)(crow + 4) = o1;
  }
}

// ---------------------------------------------------------------------------
// Persistent sequential LSTM scan — round-3 proven structure (1805-1830 us,
// register-resident weights, no spill) with ONE change this round:
// poll compression. Each poll iteration was 4 separate dword agent-scope
// loads; chip-wide that is ~655 L3 requests/cycle (128 L0-blocks x 256
// pollers x 4 + 128 L1-blocks x 512 x 4 every ~600cy poll period), all
// forced past the non-coherent XCD L2s — L3 request-rate saturation theory
// for the 8570 cy/step (vs ~2300 cy chain arithmetic). Now: one
// global_load_dwordx4 sc0 sc1 per iteration (same bytes, same per-word
// sentinel semantics, 4x fewer requests).
//
// 256 blocks x 512 threads. Blocks 0..127: layer 0. Blocks 128..255: layer 1
// (lags one step). Block owns hidden units [8b, 8b+8) + their c. Wave w =
// (gate w>>1, K-half w&1). Sync = sentinel-in-data: h histories pre-filled
// with 2.0f (h in [-1,1] can't produce it); consumers poll data words
// directly. Hot-spin 16 iters then s_sleep(1).
// ---------------------------------------------------------------------------
__global__ __launch_bounds__(512, 2) void lstm_seq_k(
    const float* __restrict__ Whh0,
    const float* __restrict__ Wih1,
    const float* __restrict__ Whh1,
    const float* __restrict__ bih1,
    const float* __restrict__ bhh1,
    const float* __restrict__ G0,
    float* __restrict__ h0h, float* __restrict__ h1h,   // (T+1) x 1024, sentinel
    float* __restrict__ h1out,                          // (512,1024) FC input
    float* __restrict__ out_hc)                         // h(2x1024) then c(2x1024)
{
  const int layer = blockIdx.x >> 7;
  const int b     = blockIdx.x & 127;
  const int jbase = b * 8;
  const int tid   = threadIdx.x;
  const int w     = tid >> 6;      // 0..7
  const int g     = w >> 1;        // gate i,f,g,o
  const int hh    = w & 1;         // k-half
  const int lane  = tid & 63;

  __shared__ __align__(16) float hbuf[2048];
  __shared__ float gbuf[8][8];
  __shared__ float cbuf[8];
  if (tid < 8) cbuf[tid] = 0.f;

  if (layer == 0) {
    // ---- L0: K=1024; wave covers k in [hh*512, hh*512+512); 64 wVGPR ----
    float wr[8][8];
    #pragma unroll
    for (int j = 0; j < 8; ++j) {
      const float* p = Whh0 + (size_t)(g*1024 + jbase + j) * 1024 + hh*512 + lane*4;
      #pragma unroll
      for (int q = 0; q < 2; ++q) {
        float4 v = *(const float4*)(p + q*256);
        wr[j][q*4+0]=v.x; wr[j][q*4+1]=v.y; wr[j][q*4+2]=v.z; wr[j][q*4+3]=v.w;
      }
    }
    __syncthreads();
    for (int t = 0; t < T_STEPS; ++t) {
      // G0 prefetch (independent of poll)
      float g0v[4] = {0.f,0.f,0.f,0.f};
      if (tid < 8) {
        const float* g0 = G0 + (size_t)t*4096 + jbase + tid;
        #pragma unroll
        for (int q = 0; q < 4; ++q) g0v[q] = g0[q*1024];
      }
      if (tid < 256) {        // poll+stage h0h[t]: data IS the flag
        const float* p = h0h + (size_t)t * H_DIM + tid*4;
        f4_t v; int sp = 0;
        for (;;) {
          v = poll4(p);
          if (__float_as_uint(v.x) != SENTU && __float_as_uint(v.y) != SENTU &&
              __float_as_uint(v.z) != SENTU && __float_as_uint(v.w) != SENTU) break;
          if (++sp > 16) __builtin_amdgcn_s_sleep(1);
          if (sp > SPIN_CAP) break;
        }
        *(f4_t*)&hbuf[tid*4] = v;
      }
      __syncthreads();
      float acc[8];
      {
        float4 xv0 = *(const float4*)&hbuf[hh*512 + lane*4];
        float4 xv1 = *(const float4*)&hbuf[hh*512 + 256 + lane*4];
        #pragma unroll
        for (int j = 0; j < 8; ++j)
          acc[j] = wr[j][0]*xv0.x + wr[j][1]*xv0.y + wr[j][2]*xv0.z + wr[j][3]*xv0.w +
                   wr[j][4]*xv1.x + wr[j][5]*xv1.y + wr[j][6]*xv1.z + wr[j][7]*xv1.w;
      }
      #pragma unroll
      for (int j = 0; j < 8; ++j)
        #pragma unroll
        for (int msk = 1; msk < 64; msk <<= 1)
          acc[j] += __shfl_xor(acc[j], msk, 64);
      if (lane == 0) {
        #pragma unroll
        for (int j = 0; j < 8; ++j) gbuf[w][j] = acc[j];
      }
      __syncthreads();
      if (tid < 8) {
        const int j = tid;
        float iv = sigmoid_f(gbuf[0][j] + gbuf[1][j] + g0v[0]);
        float fv = sigmoid_f(gbuf[2][j] + gbuf[3][j] + g0v[1]);
        float gv = tanhf   (gbuf[4][j] + gbuf[5][j] + g0v[2]);
        float ov = sigmoid_f(gbuf[6][j] + gbuf[7][j] + g0v[3]);
        float c  = fv * cbuf[j] + iv * gv;
        cbuf[j]  = c;
        float h  = ov * tanhf(c);
        gastore(&h0h[(size_t)(t+1)*H_DIM + jbase + j], h);
        if (t == T_STEPS - 1) { out_hc[jbase + j] = h; out_hc[2048 + jbase + j] = c; }
      }
    }
  } else {
    // ---- L1: K=2048 concat [y[t]; h1[t-1]]; wave covers 1024 k; 128 wVGPR ----
    float wr[8][16];
    {
      const float* base = hh ? Whh1 : Wih1;
      #pragma unroll
      for (int j = 0; j < 8; ++j) {
        const float* p = base + (size_t)(g*1024 + jbase + j) * 1024 + lane*4;
        #pragma unroll
        for (int q = 0; q < 4; ++q) {
          float4 v = *(const float4*)(p + q*256);
          wr[j][q*4+0]=v.x; wr[j][q*4+1]=v.y; wr[j][q*4+2]=v.z; wr[j][q*4+3]=v.w;
        }
      }
    }
    float bi1[4] = {0.f,0.f,0.f,0.f};
    if (tid < 8) {
      int j = jbase + tid;
      #pragma unroll
      for (int q = 0; q < 4; ++q) bi1[q] = bih1[q*1024 + j] + bhh1[q*1024 + j];
    }
    __syncthreads();
    for (int t = 0; t < T_STEPS; ++t) {
      { // poll+stage [h0h[t+1] ; h1h[t]] — 512 threads x 1 dwordx4
        const float* p = (tid < 256) ? (h0h + (size_t)(t+1)*H_DIM + tid*4)
                                     : (h1h + (size_t)t*H_DIM + (tid-256)*4);
        f4_t v; int sp = 0;
        for (;;) {
          v = poll4(p);
          if (__float_as_uint(v.x) != SENTU && __float_as_uint(v.y) != SENTU &&
              __float_as_uint(v.z) != SENTU && __float_as_uint(v.w) != SENTU) break;
          if (++sp > 16) __builtin_amdgcn_s_sleep(1);
          if (sp > SPIN_CAP) break;
        }
        *(f4_t*)&hbuf[tid*4] = v;
      }
      __syncthreads();
      float acc[8];
      {
        float4 xv[4];
        #pragma unroll
        for (int q = 0; q < 4; ++q)
          xv[q] = *(const float4*)&hbuf[hh*1024 + q*256 + lane*4];
        #pragma unroll
        for (int j = 0; j < 8; ++j) {
          float s = 0.f;
          #pragma unroll
          for (int q = 0; q < 4; ++q)
            s += wr[j][q*4+0]*xv[q].x + wr[j][q*4+1]*xv[q].y +
                 wr[j][q*4+2]*xv[q].z + wr[j][q*4+3]*xv[q].w;
          acc[j] = s;
        }
      }
      #pragma unroll
      for (int j = 0; j < 8; ++j)
        #pragma unroll
        for (int msk = 1; msk < 64; msk <<= 1)
          acc[j] += __shfl_xor(acc[j], msk, 64);
      if (lane == 0) {
        #pragma unroll
        for (int j = 0; j < 8; ++j) gbuf[w][j] = acc[j];
      }
      __syncthreads();
      if (tid < 8) {
        const int j = tid;
        float iv = sigmoid_f(gbuf[0][j] + gbuf[1][j] + bi1[0]);
        float fv = sigmoid_f(gbuf[2][j] + gbuf[3][j] + bi1[1]);
        float gv = tanhf   (gbuf[4][j] + gbuf[5][j] + bi1[2]);
        float ov = sigmoid_f(gbuf[6][j] + gbuf[7][j] + bi1[3]);
        float c  = fv * cbuf[j] + iv * gv;
        cbuf[j]  = c;
        float h  = ov * tanhf(c);
        gastore(&h1h[(size_t)(t+1)*H_DIM + jbase + j], h);
        h1out[(size_t)t*H_DIM + jbase + j] = h;
        if (t == T_STEPS - 1) { out_hc[1024 + jbase + j] = h; out_hc[3072 + jbase + j] = c; }
      }
    }
  }
}

// ---------------------------------------------------------------------------
// split_a_k: h1out (512x1024 fp32) -> A_hi, A_lo (bf16 pair), row-major [m][k].
// ---------------------------------------------------------------------------
__global__ void split_a_k(const float* __restrict__ A,
                          ushort_t* __restrict__ Ahi, ushort_t* __restrict__ Alo)
{
  int i = (blockIdx.x * blockDim.x + threadIdx.x) * 4;
  if (i >= T_STEPS * H_DIM) return;
  float4 v = *(const float4*)(A + i);
  ushort4 h, l;
  split2(v.x, h.x, l.x); split2(v.y, h.y, l.y);
  split2(v.z, h.z, l.z); split2(v.w, h.w, l.w);
  *(ushort4*)(Ahi + i) = h;
  *(ushort4*)(Alo + i) = l;
}

// ---------------------------------------------------------------------------
// fc_mfma_k: scores = A @ W^T + b via split-bf16 (bf16x3) MFMA.  (unchanged)
//   C[m][n] ~ Ah*Wh + Ah*Wl + Al*Wh   (Al*Wl ~2^-18 rel, dropped)
// Tile 256x128, BK=32, 512 threads = 8 waves (4M x 2N), wave tile 64x64 =
// 4x4 x mfma_f32_16x16x32_bf16. Reg-staged loads for tile k+1 issued before
// compute of tile k (T14-lite).
// ---------------------------------------------------------------------------
typedef __attribute__((ext_vector_type(8))) short bf16x8;
typedef __attribute__((ext_vector_type(4))) float f32x4;

#define FBM 256
#define FBN 128
#define FBK 32
#define FPITCH 40   // 32 + 8 pad, bf16 elements per LDS row

__global__ __launch_bounds__(512, 2) void fc_mfma_k(
    const ushort_t* __restrict__ Ahi, const ushort_t* __restrict__ Alo,
    const float* __restrict__ W,      // (32000,1024) fp32
    const float* __restrict__ bias,   // (32000)
    float* __restrict__ C)            // (512,32000)
{
  __shared__ __align__(16) ushort_t Ah[FBM * FPITCH];
  __shared__ __align__(16) ushort_t Al[FBM * FPITCH];
  __shared__ __align__(16) ushort_t Wh[FBN * FPITCH];
  __shared__ __align__(16) ushort_t Wl[FBN * FPITCH];

  const int tid  = threadIdx.x;
  const int m0   = blockIdx.y * FBM;
  const int n0   = blockIdx.x * FBN;
  const int wid  = tid >> 6, lane = tid & 63;
  const int wm   = wid & 3, wn = wid >> 2;        // wave tile (wm*64, wn*64)
  const int frow = lane & 15, fk = (lane >> 4) * 8;

  f32x4 acc[4][4] = {};   // acc[mt][nt]

  // staged-tile registers
  uint4 rah0, rah1, ral0, ral1;
  float4 rw0, rw1;

  auto LOADTILE = [&](int kt) {
    { int c = tid;       int r = c >> 2, kc = (c & 3) * 8;
      size_t off = (size_t)(m0 + r) * 1024 + kt * FBK + kc;
      rah0 = *(const uint4*)(Ahi + off);
      ral0 = *(const uint4*)(Alo + off); }
    { int c = tid + 512; int r = c >> 2, kc = (c & 3) * 8;
      size_t off = (size_t)(m0 + r) * 1024 + kt * FBK + kc;
      rah1 = *(const uint4*)(Ahi + off);
      ral1 = *(const uint4*)(Alo + off); }
    { int c = tid;       int r = c >> 3, kc = (c & 7) * 4;
      rw0 = *(const float4*)(W + (size_t)(n0 + r) * 1024 + kt * FBK + kc); }
    { int c = tid + 512; int r = c >> 3, kc = (c & 7) * 4;
      rw1 = *(const float4*)(W + (size_t)(n0 + r) * 1024 + kt * FBK + kc); }
  };
  auto STORETILE = [&]() {
    { int c = tid;       int r = c >> 2, kc = (c & 3) * 8;
      *(uint4*)&Ah[r * FPITCH + kc] = rah0;
      *(uint4*)&Al[r * FPITCH + kc] = ral0; }
    { int c = tid + 512; int r = c >> 2, kc = (c & 3) * 8;
      *(uint4*)&Ah[r * FPITCH + kc] = rah1;
      *(uint4*)&Al[r * FPITCH + kc] = ral1; }
    { int c = tid;       int r = c >> 3, kc = (c & 7) * 4;
      ushort4 h, l;
      split2(rw0.x, h.x, l.x); split2(rw0.y, h.y, l.y);
      split2(rw0.z, h.z, l.z); split2(rw0.w, h.w, l.w);
      *(ushort4*)&Wh[r * FPITCH + kc] = h;
      *(ushort4*)&Wl[r * FPITCH + kc] = l; }
    { int c = tid + 512; int r = c >> 3, kc = (c & 7) * 4;
      ushort4 h, l;
      split2(rw1.x, h.x, l.x); split2(rw1.y, h.y, l.y);
      split2(rw1.z, h.z, l.z); split2(rw1.w, h.w, l.w);
      *(ushort4*)&Wh[r * FPITCH + kc] = h;
      *(ushort4*)&Wl[r * FPITCH + kc] = l; }
  };

  LOADTILE(0);
  const int NK = 1024 / FBK;
  for (int kt = 0; kt < NK; ++kt) {
    __syncthreads();            // prev tile's LDS consumers done
    STORETILE();
    __syncthreads();
    if (kt + 1 < NK) LOADTILE(kt + 1);   // overlap next loads with compute

    bf16x8 bh[4], bl[4];
    #pragma unroll
    for (int nt = 0; nt < 4; ++nt) {
      int br = (wn * 64 + nt * 16 + frow) * FPITCH + fk;
      bh[nt] = *(const bf16x8*)&Wh[br];
      bl[nt] = *(const bf16x8*)&Wl[br];
    }
    #pragma unroll
    for (int mt = 0; mt < 4; ++mt) {
      int ar = (wm * 64 + mt * 16 + frow) * FPITCH + fk;
      bf16x8 ah = *(const bf16x8*)&Ah[ar];
      bf16x8 al = *(const bf16x8*)&Al[ar];
      #pragma unroll
      for (int nt = 0; nt < 4; ++nt) {
        acc[mt][nt] = __builtin_amdgcn_mfma_f32_16x16x32_bf16(ah, bh[nt], acc[mt][nt], 0, 0, 0);
        acc[mt][nt] = __builtin_amdgcn_mfma_f32_16x16x32_bf16(ah, bl[nt], acc[mt][nt], 0, 0, 0);
        acc[mt][nt] = __builtin_amdgcn_mfma_f32_16x16x32_bf16(al, bh[nt], acc[mt][nt], 0, 0, 0);
      }
    }
  }

  // epilogue: C/D map col=lane&15, row=(lane>>4)*4+reg
  #pragma unroll
  for (int nt = 0; nt < 4; ++nt) {
    int col = n0 + wn * 64 + nt * 16 + frow;
    float bv = bias[col];
    #pragma unroll
    for (int mt = 0; mt < 4; ++mt) {
      int rbase = m0 + wm * 64 + mt * 16 + (lane >> 4) * 4;
      #pragma unroll
      for (int r = 0; r < 4; ++r)
        C[(size_t)(rbase + r) * VOCAB + col] = acc[mt][nt][r] + bv;
    }
  }
}

// ---------------------------------------------------------------------------
extern "C" void kernel_launch(void* const* d_in, const int* in_sizes, int n_in,
                              void* d_out, int out_size, void* d_ws, size_t ws_size,
                              hipStream_t stream)
{
  (void)in_sizes; (void)n_in; (void)out_size; (void)ws_size;
  const int*   x    = (const int*)  d_in[0];
  const float* emb  = (const float*)d_in[1];
  const float* W_ih = (const float*)d_in[2];   // (2, 4096, 1024)
  const float* W_hh = (const float*)d_in[3];
  const float* b_ih = (const float*)d_in[4];   // (2, 4096)
  const float* b_hh = (const float*)d_in[5];
  const float* W_fc = (const float*)d_in[6];   // (32000, 1024)
  const float* b_fc = (const float*)d_in[7];
  float* out = (float*)d_out;                  // scores(512x32000) | h(2x1024) | c(2x1024)

  // workspace layout (floats); ~16.3 MB total
  float* ws    = (float*)d_ws;
  float* G0    = ws;                                         // 512*4096
  float* h0h   = G0   + (size_t)T_STEPS * 4096;              // 513*1024
  float* h1h   = h0h  + (size_t)(T_STEPS + 1) * H_DIM;       // 513*1024
  float* h1out = h1h  + (size_t)(T_STEPS + 1) * H_DIM;       // 512*1024
  int*   xmap  = (int*)(h1out + (size_t)T_STEPS * H_DIM);    // 512 ints
  ushort_t* Ahi = (ushort_t*)(xmap + 512);                   // 512*1024 bf16
  ushort_t* Alo = Ahi + (size_t)T_STEPS * H_DIM;             // 512*1024 bf16

  init_ws_k<<<128, 256, 0, stream>>>(x, h0h, h1h, xmap);

  // G0[t,:] = W_ih0 @ emb[x_t] + b_ih0 + b_hh0   (512 x 4096)
  gemm_atb_k<<<dim3(4096 / BN, T_STEPS / BM), 256, 0, stream>>>(
      nullptr, emb, xmap, W_ih, b_ih, b_hh, G0, T_STEPS, 4096, 1024);

  // sequential scan (two layer domains, sentinel signaling, compressed poll)
  lstm_seq_k<<<256, 512, 0, stream>>>(
      W_hh, W_ih + (size_t)4096 * 1024, W_hh + (size_t)4096 * 1024,
      b_ih + 4096, b_hh + 4096, G0, h0h, h1h, h1out,
      out + (size_t)T_STEPS * VOCAB);

  // split FC input to bf16 hi/lo
  split_a_k<<<(T_STEPS * H_DIM / 4 + 255) / 256, 256, 0, stream>>>(h1out, Ahi, Alo);

  // scores = outs @ W_fc^T + b_fc  (split-bf16 MFMA)
  fc_mfma_k<<<dim3(VOCAB / FBN, T_STEPS / FBM), 512, 0, stream>>>(
      Ahi, Alo, W_fc, b_fc, out);
}

// Round 4
// 1808.580 us; speedup vs baseline: 1.9888x; 1.1522x over previous
//
#include <hip/hip_runtime.h>
#include <cstdint>
#include <cstddef>

// Problem constants
#define H_DIM   1024
#define T_STEPS 512           // L*N = 64*8 flattened time-major
#define VOCAB   32000
#define SENTU   0x40000000u   // 2.0f — unreachable: h = o*tanh(c) in [-1,1]
#define SPIN_CAP 5000000      // hang guard

typedef unsigned int  uint_t;
typedef unsigned short ushort_t;
typedef float __attribute__((ext_vector_type(4))) f4_t;

__device__ __forceinline__ float gaload(const float* p) {
  return __hip_atomic_load(const_cast<float*>(p), __ATOMIC_RELAXED, __HIP_MEMORY_SCOPE_AGENT);
}
__device__ __forceinline__ void gastore(float* p, float v) {
  __hip_atomic_store(p, v, __ATOMIC_RELAXED, __HIP_MEMORY_SCOPE_AGENT);
}
// One 16B coherent load (bypasses non-coherent XCD L2 via sc0 sc1) replacing
// 4 dword agent-scope loads (round-3 win: -220us). waitcnt fused in the same
// asm block so consumers can't be scheduled before data lands.
__device__ __forceinline__ f4_t poll4(const float* p) {
  f4_t v;
  asm volatile("global_load_dwordx4 %0, %1, off sc0 sc1\n\ts_waitcnt vmcnt(0)"
               : "=v"(v) : "v"(p) : "memory");
  return v;
}
__device__ __forceinline__ float sigmoid_f(float v) { return 1.f / (1.f + expf(-v)); }

// ---------------------------------------------------------------------------
// Wave64 sum with minimal LDS-pipe traffic (round 4 change).
// Old: 6x __shfl_xor per value = 6 ds_bpermute -> 48 DS ops/wave, 384/block,
// serialized on the CU's single LDS pipe (~6cy each, m134) ~= 2300 cy/step.
// New: stages ^1,^2 via quad_perm DPP, within-8 and within-16 via
// row_half_mirror / row_mirror DPP (mirror pairing is a valid butterfly for
// a commutative sum: each lane pairs with the other half of its group) —
// all VALU, 4 SIMDs in parallel. Only ^16 (ds_swizzle 0x401F) and ^32
// (shfl_xor) touch the LDS pipe: 2 DS ops per value instead of 6.
// ---------------------------------------------------------------------------
template<int CTRL>
__device__ __forceinline__ float dpp_add(float x) {
  int y = __builtin_amdgcn_update_dpp(0, __float_as_int(x), CTRL, 0xF, 0xF, true);
  return x + __int_as_float(y);
}
__device__ __forceinline__ float wave64_sum(float x) {
  x = dpp_add<0xB1>(x);    // quad_perm(1,0,3,2)  : xor 1
  x = dpp_add<0x4E>(x);    // quad_perm(2,3,0,1)  : xor 2
  x = dpp_add<0x141>(x);   // row_half_mirror     : pair with other quad of 8
  x = dpp_add<0x140>(x);   // row_mirror          : pair with other 8 of 16
  x += __int_as_float(__builtin_amdgcn_ds_swizzle(__float_as_int(x), 0x401F)); // xor 16
  x += __shfl_xor(x, 32, 64);                                                  // xor 32
  return x;
}

// fp32 -> bf16 (RNE) and two-term split: x ~= hi + lo, |err| ~ 2^-17 |x|
__device__ __forceinline__ ushort_t bf_rne(float x) {
  uint_t u = __float_as_uint(x);
  return (ushort_t)((u + 0x7FFFu + ((u >> 16) & 1u)) >> 16);
}
__device__ __forceinline__ void split2(float x, ushort_t& h, ushort_t& l) {
  h = bf_rne(x);
  float hf = __uint_as_float(((uint_t)h) << 16);
  l = bf_rne(x - hf);
}

// ---------------------------------------------------------------------------
// init: h0h/h1h slot 0 = zeros (initial state), slots 1..512 = sentinel.
// xmap[t] = x[n,l] time-major gather map.
// ---------------------------------------------------------------------------
__global__ void init_ws_k(const int* __restrict__ x,
                          float* __restrict__ h0h, float* __restrict__ h1h,
                          int* __restrict__ xmap)
{
  int tid = blockIdx.x * blockDim.x + threadIdx.x;
  int nt  = gridDim.x * blockDim.x;
  const float sent = __uint_as_float(SENTU);
  for (int i = tid; i < (T_STEPS + 1) * H_DIM; i += nt) {
    float v = (i < H_DIM) ? 0.f : sent;
    h0h[i] = v; h1h[i] = v;
  }
  for (int t = tid; t < T_STEPS; t += nt) xmap[t] = x[(t & 7) * 64 + (t >> 3)];
}

// ---------------------------------------------------------------------------
// fp32 GEMM  C[M,N] = A[M,K] @ B[N,K]^T + bias0 + bias1.  (used for G0 only)
// If A==null, row t of A is gathered as emb[xmap[t]].
// 128x128 tile, BK=16, 256 threads, 8x8 per-thread microtile.
// ---------------------------------------------------------------------------
#define BM 128
#define BN 128
#define BKD 16

__global__ __launch_bounds__(256) void gemm_atb_k(
    const float* __restrict__ A, const float* __restrict__ emb,
    const int* __restrict__ xmap,
    const float* __restrict__ B,
    const float* __restrict__ bias0, const float* __restrict__ bias1,
    float* __restrict__ C, int M, int N, int K)
{
  __shared__ __align__(16) float As[BKD][BM + 4];
  __shared__ __align__(16) float Bs[BKD][BN + 4];
  const int tid = threadIdx.x;
  const int tx = tid & 15, ty = tid >> 4;
  const int m0 = blockIdx.y * BM, n0 = blockIdx.x * BN;
  const int lr = tid >> 1;           // 0..127: row within tile
  const int lk = (tid & 1) * 8;      // 0 or 8: k sub-chunk
  const float* arow = A ? (A + (size_t)(m0 + lr) * K)
                        : (emb + (size_t)xmap[m0 + lr] * K);
  const float* brow = B + (size_t)(n0 + lr) * K;

  float acc[8][8];
  #pragma unroll
  for (int i = 0; i < 8; ++i)
    #pragma unroll
    for (int j = 0; j < 8; ++j) acc[i][j] = 0.f;

  for (int k0 = 0; k0 < K; k0 += BKD) {
    float4 a0 = *(const float4*)(arow + k0 + lk);
    float4 a1 = *(const float4*)(arow + k0 + lk + 4);
    float4 b0 = *(const float4*)(brow + k0 + lk);
    float4 b1 = *(const float4*)(brow + k0 + lk + 4);
    __syncthreads();   // protect previous iteration's LDS reads
    As[lk+0][lr]=a0.x; As[lk+1][lr]=a0.y; As[lk+2][lr]=a0.z; As[lk+3][lr]=a0.w;
    As[lk+4][lr]=a1.x; As[lk+5][lr]=a1.y; As[lk+6][lr]=a1.z; As[lk+7][lr]=a1.w;
    Bs[lk+0][lr]=b0.x; Bs[lk+1][lr]=b0.y; Bs[lk+2][lr]=b0.z; Bs[lk+3][lr]=b0.w;
    Bs[lk+4][lr]=b1.x; Bs[lk+5][lr]=b1.y; Bs[lk+6][lr]=b1.z; Bs[lk+7][lr]=b1.w;
    __syncthreads();
    #pragma unroll
    for (int kk = 0; kk < BKD; ++kk) {
      float4 av0 = *(const float4*)&As[kk][ty*8];
      float4 av1 = *(const float4*)&As[kk][ty*8+4];
      float4 bv0 = *(const float4*)&Bs[kk][tx*8];
      float4 bv1 = *(const float4*)&Bs[kk][tx*8+4];
      float av[8] = {av0.x,av0.y,av0.z,av0.w,av1.x,av1.y,av1.z,av1.w};
      float bv[8] = {bv0.x,bv0.y,bv0.z,bv0.w,bv1.x,bv1.y,bv1.z,bv1.w};
      #pragma unroll
      for (int i = 0; i < 8; ++i)
        #pragma unroll
        for (int j = 0; j < 8; ++j) acc[i][j] += av[i] * bv[j];
    }
  }
  float bvp[8];
  #pragma unroll
  for (int j = 0; j < 8; ++j) {
    int n = n0 + tx*8 + j;
    float s = 0.f;
    if (bias0) s += bias0[n];
    if (bias1) s += bias1[n];
    bvp[j] = s;
  }
  #pragma unroll
  for (int i = 0; i < 8; ++i) {
    int m = m0 + ty*8 + i;
    float* crow = C + (size_t)m * N + n0 + tx*8;
    float4 o0, o1;
    o0.x=acc[i][0]+bvp[0]; o0.y=acc[i][1]+bvp[1]; o0.z=acc[i][2]+bvp[2]; o0.w=acc[i][3]+bvp[3];
    o1.x=acc[i][4]+bvp[4]; o1.y=acc[i][5]+bvp[5]; o1.z=acc[i][6]+bvp[6]; o1.w=acc[i][7]+bvp[7];
    *(float4*)crow = o0;
    *(float4*)(crow + 4) = o1;
  }
}

// ---------------------------------------------------------------------------
// Persistent sequential LSTM scan — round-3 structure + compressed poll
// (1608 us) with ONE change this round: DPP-based wave reduce (see
// wave64_sum above). 384 -> ~128 LDS-pipe ops per block per step.
//
// 256 blocks x 512 threads. Blocks 0..127: layer 0. Blocks 128..255: layer 1
// (lags one step). Block owns hidden units [8b, 8b+8) + their c. Wave w =
// (gate w>>1, K-half w&1). Sync = sentinel-in-data: h histories pre-filled
// with 2.0f (h in [-1,1] can't produce it); consumers poll data words
// directly. Hot-spin 16 iters then s_sleep(1).
// ---------------------------------------------------------------------------
__global__ __launch_bounds__(512, 2) void lstm_seq_k(
    const float* __restrict__ Whh0,
    const float* __restrict__ Wih1,
    const float* __restrict__ Whh1,
    const float* __restrict__ bih1,
    const float* __restrict__ bhh1,
    const float* __restrict__ G0,
    float* __restrict__ h0h, float* __restrict__ h1h,   // (T+1) x 1024, sentinel
    float* __restrict__ h1out,                          // (512,1024) FC input
    float* __restrict__ out_hc)                         // h(2x1024) then c(2x1024)
{
  const int layer = blockIdx.x >> 7;
  const int b     = blockIdx.x & 127;
  const int jbase = b * 8;
  const int tid   = threadIdx.x;
  const int w     = tid >> 6;      // 0..7
  const int g     = w >> 1;        // gate i,f,g,o
  const int hh    = w & 1;         // k-half
  const int lane  = tid & 63;

  __shared__ __align__(16) float hbuf[2048];
  __shared__ float gbuf[8][8];
  __shared__ float cbuf[8];
  if (tid < 8) cbuf[tid] = 0.f;

  if (layer == 0) {
    // ---- L0: K=1024; wave covers k in [hh*512, hh*512+512); 64 wVGPR ----
    float wr[8][8];
    #pragma unroll
    for (int j = 0; j < 8; ++j) {
      const float* p = Whh0 + (size_t)(g*1024 + jbase + j) * 1024 + hh*512 + lane*4;
      #pragma unroll
      for (int q = 0; q < 2; ++q) {
        float4 v = *(const float4*)(p + q*256);
        wr[j][q*4+0]=v.x; wr[j][q*4+1]=v.y; wr[j][q*4+2]=v.z; wr[j][q*4+3]=v.w;
      }
    }
    __syncthreads();
    for (int t = 0; t < T_STEPS; ++t) {
      // G0 prefetch (independent of poll)
      float g0v[4] = {0.f,0.f,0.f,0.f};
      if (tid < 8) {
        const float* g0 = G0 + (size_t)t*4096 + jbase + tid;
        #pragma unroll
        for (int q = 0; q < 4; ++q) g0v[q] = g0[q*1024];
      }
      if (tid < 256) {        // poll+stage h0h[t]: data IS the flag
        const float* p = h0h + (size_t)t * H_DIM + tid*4;
        f4_t v; int sp = 0;
        for (;;) {
          v = poll4(p);
          if (__float_as_uint(v.x) != SENTU && __float_as_uint(v.y) != SENTU &&
              __float_as_uint(v.z) != SENTU && __float_as_uint(v.w) != SENTU) break;
          if (++sp > 16) __builtin_amdgcn_s_sleep(1);
          if (sp > SPIN_CAP) break;
        }
        *(f4_t*)&hbuf[tid*4] = v;
      }
      __syncthreads();
      float acc[8];
      {
        float4 xv0 = *(const float4*)&hbuf[hh*512 + lane*4];
        float4 xv1 = *(const float4*)&hbuf[hh*512 + 256 + lane*4];
        #pragma unroll
        for (int j = 0; j < 8; ++j)
          acc[j] = wr[j][0]*xv0.x + wr[j][1]*xv0.y + wr[j][2]*xv0.z + wr[j][3]*xv0.w +
                   wr[j][4]*xv1.x + wr[j][5]*xv1.y + wr[j][6]*xv1.z + wr[j][7]*xv1.w;
      }
      #pragma unroll
      for (int j = 0; j < 8; ++j) acc[j] = wave64_sum(acc[j]);
      if (lane == 0) {
        #pragma unroll
        for (int j = 0; j < 8; ++j) gbuf[w][j] = acc[j];
      }
      __syncthreads();
      if (tid < 8) {
        const int j = tid;
        float iv = sigmoid_f(gbuf[0][j] + gbuf[1][j] + g0v[0]);
        float fv = sigmoid_f(gbuf[2][j] + gbuf[3][j] + g0v[1]);
        float gv = tanhf   (gbuf[4][j] + gbuf[5][j] + g0v[2]);
        float ov = sigmoid_f(gbuf[6][j] + gbuf[7][j] + g0v[3]);
        float c  = fv * cbuf[j] + iv * gv;
        cbuf[j]  = c;
        float h  = ov * tanhf(c);
        gastore(&h0h[(size_t)(t+1)*H_DIM + jbase + j], h);
        if (t == T_STEPS - 1) { out_hc[jbase + j] = h; out_hc[2048 + jbase + j] = c; }
      }
    }
  } else {
    // ---- L1: K=2048 concat [y[t]; h1[t-1]]; wave covers 1024 k; 128 wVGPR ----
    float wr[8][16];
    {
      const float* base = hh ? Whh1 : Wih1;
      #pragma unroll
      for (int j = 0; j < 8; ++j) {
        const float* p = base + (size_t)(g*1024 + jbase + j) * 1024 + lane*4;
        #pragma unroll
        for (int q = 0; q < 4; ++q) {
          float4 v = *(const float4*)(p + q*256);
          wr[j][q*4+0]=v.x; wr[j][q*4+1]=v.y; wr[j][q*4+2]=v.z; wr[j][q*4+3]=v.w;
        }
      }
    }
    float bi1[4] = {0.f,0.f,0.f,0.f};
    if (tid < 8) {
      int j = jbase + tid;
      #pragma unroll
      for (int q = 0; q < 4; ++q) bi1[q] = bih1[q*1024 + j] + bhh1[q*1024 + j];
    }
    __syncthreads();
    for (int t = 0; t < T_STEPS; ++t) {
      { // poll+stage [h0h[t+1] ; h1h[t]] — 512 threads x 1 dwordx4
        const float* p = (tid < 256) ? (h0h + (size_t)(t+1)*H_DIM + tid*4)
                                     : (h1h + (size_t)t*H_DIM + (tid-256)*4);
        f4_t v; int sp = 0;
        for (;;) {
          v = poll4(p);
          if (__float_as_uint(v.x) != SENTU && __float_as_uint(v.y) != SENTU &&
              __float_as_uint(v.z) != SENTU && __float_as_uint(v.w) != SENTU) break;
          if (++sp > 16) __builtin_amdgcn_s_sleep(1);
          if (sp > SPIN_CAP) break;
        }
        *(f4_t*)&hbuf[tid*4] = v;
      }
      __syncthreads();
      float acc[8];
      {
        float4 xv[4];
        #pragma unroll
        for (int q = 0; q < 4; ++q)
          xv[q] = *(const float4*)&hbuf[hh*1024 + q*256 + lane*4];
        #pragma unroll
        for (int j = 0; j < 8; ++j) {
          float s = 0.f;
          #pragma unroll
          for (int q = 0; q < 4; ++q)
            s += wr[j][q*4+0]*xv[q].x + wr[j][q*4+1]*xv[q].y +
                 wr[j][q*4+2]*xv[q].z + wr[j][q*4+3]*xv[q].w;
          acc[j] = s;
        }
      }
      #pragma unroll
      for (int j = 0; j < 8; ++j) acc[j] = wave64_sum(acc[j]);
      if (lane == 0) {
        #pragma unroll
        for (int j = 0; j < 8; ++j) gbuf[w][j] = acc[j];
      }
      __syncthreads();
      if (tid < 8) {
        const int j = tid;
        float iv = sigmoid_f(gbuf[0][j] + gbuf[1][j] + bi1[0]);
        float fv = sigmoid_f(gbuf[2][j] + gbuf[3][j] + bi1[1]);
        float gv = tanhf   (gbuf[4][j] + gbuf[5][j] + bi1[2]);
        float ov = sigmoid_f(gbuf[6][j] + gbuf[7][j] + bi1[3]);
        float c  = fv * cbuf[j] + iv * gv;
        cbuf[j]  = c;
        float h  = ov * tanhf(c);
        gastore(&h1h[(size_t)(t+1)*H_DIM + jbase + j], h);
        h1out[(size_t)t*H_DIM + jbase + j] = h;
        if (t == T_STEPS - 1) { out_hc[1024 + jbase + j] = h; out_hc[3072 + jbase + j] = c; }
      }
    }
  }
}

// ---------------------------------------------------------------------------
// split_a_k: h1out (512x1024 fp32) -> A_hi, A_lo (bf16 pair), row-major [m][k].
// ---------------------------------------------------------------------------
__global__ void split_a_k(const float* __restrict__ A,
                          ushort_t* __restrict__ Ahi, ushort_t* __restrict__ Alo)
{
  int i = (blockIdx.x * blockDim.x + threadIdx.x) * 4;
  if (i >= T_STEPS * H_DIM) return;
  float4 v = *(const float4*)(A + i);
  ushort4 h, l;
  split2(v.x, h.x, l.x); split2(v.y, h.y, l.y);
  split2(v.z, h.z, l.z); split2(v.w, h.w, l.w);
  *(ushort4*)(Ahi + i) = h;
  *(ushort4*)(Alo + i) = l;
}

// ---------------------------------------------------------------------------
// fc_mfma_k: scores = A @ W^T + b via split-bf16 (bf16x3) MFMA.  (unchanged)
//   C[m][n] ~ Ah*Wh + Ah*Wl + Al*Wh   (Al*Wl ~2^-18 rel, dropped)
// Tile 256x128, BK=32, 512 threads = 8 waves (4M x 2N), wave tile 64x64 =
// 4x4 x mfma_f32_16x16x32_bf16. Reg-staged loads for tile k+1 issued before
// compute of tile k (T14-lite).
// ---------------------------------------------------------------------------
typedef __attribute__((ext_vector_type(8))) short bf16x8;
typedef __attribute__((ext_vector_type(4))) float f32x4;

#define FBM 256
#define FBN 128
#define FBK 32
#define FPITCH 40   // 32 + 8 pad, bf16 elements per LDS row

__global__ __launch_bounds__(512, 2) void fc_mfma_k(
    const ushort_t* __restrict__ Ahi, const ushort_t* __restrict__ Alo,
    const float* __restrict__ W,      // (32000,1024) fp32
    const float* __restrict__ bias,   // (32000)
    float* __restrict__ C)            // (512,32000)
{
  __shared__ __align__(16) ushort_t Ah[FBM * FPITCH];
  __shared__ __align__(16) ushort_t Al[FBM * FPITCH];
  __shared__ __align__(16) ushort_t Wh[FBN * FPITCH];
  __shared__ __align__(16) ushort_t Wl[FBN * FPITCH];

  const int tid  = threadIdx.x;
  const int m0   = blockIdx.y * FBM;
  const int n0   = blockIdx.x * FBN;
  const int wid  = tid >> 6, lane = tid & 63;
  const int wm   = wid & 3, wn = wid >> 2;        // wave tile (wm*64, wn*64)
  const int frow = lane & 15, fk = (lane >> 4) * 8;

  f32x4 acc[4][4] = {};   // acc[mt][nt]

  // staged-tile registers
  uint4 rah0, rah1, ral0, ral1;
  float4 rw0, rw1;

  auto LOADTILE = [&](int kt) {
    { int c = tid;       int r = c >> 2, kc = (c & 3) * 8;
      size_t off = (size_t)(m0 + r) * 1024 + kt * FBK + kc;
      rah0 = *(const uint4*)(Ahi + off);
      ral0 = *(const uint4*)(Alo + off); }
    { int c = tid + 512; int r = c >> 2, kc = (c & 3) * 8;
      size_t off = (size_t)(m0 + r) * 1024 + kt * FBK + kc;
      rah1 = *(const uint4*)(Ahi + off);
      ral1 = *(const uint4*)(Alo + off); }
    { int c = tid;       int r = c >> 3, kc = (c & 7) * 4;
      rw0 = *(const float4*)(W + (size_t)(n0 + r) * 1024 + kt * FBK + kc); }
    { int c = tid + 512; int r = c >> 3, kc = (c & 7) * 4;
      rw1 = *(const float4*)(W + (size_t)(n0 + r) * 1024 + kt * FBK + kc); }
  };
  auto STORETILE = [&]() {
    { int c = tid;       int r = c >> 2, kc = (c & 3) * 8;
      *(uint4*)&Ah[r * FPITCH + kc] = rah0;
      *(uint4*)&Al[r * FPITCH + kc] = ral0; }
    { int c = tid + 512; int r = c >> 2, kc = (c & 3) * 8;
      *(uint4*)&Ah[r * FPITCH + kc] = rah1;
      *(uint4*)&Al[r * FPITCH + kc] = ral1; }
    { int c = tid;       int r = c >> 3, kc = (c & 7) * 4;
      ushort4 h, l;
      split2(rw0.x, h.x, l.x); split2(rw0.y, h.y, l.y);
      split2(rw0.z, h.z, l.z); split2(rw0.w, h.w, l.w);
      *(ushort4*)&Wh[r * FPITCH + kc] = h;
      *(ushort4*)&Wl[r * FPITCH + kc] = l; }
    { int c = tid + 512; int r = c >> 3, kc = (c & 7) * 4;
      ushort4 h, l;
      split2(rw1.x, h.x, l.x); split2(rw1.y, h.y, l.y);
      split2(rw1.z, h.z, l.z); split2(rw1.w, h.w, l.w);
      *(ushort4*)&Wh[r * FPITCH + kc] = h;
      *(ushort4*)&Wl[r * FPITCH + kc] = l; }
  };

  LOADTILE(0);
  const int NK = 1024 / FBK;
  for (int kt = 0; kt < NK; ++kt) {
    __syncthreads();            // prev tile's LDS consumers done
    STORETILE();
    __syncthreads();
    if (kt + 1 < NK) LOADTILE(kt + 1);   // overlap next loads with compute

    bf16x8 bh[4], bl[4];
    #pragma unroll
    for (int nt = 0; nt < 4; ++nt) {
      int br = (wn * 64 + nt * 16 + frow) * FPITCH + fk;
      bh[nt] = *(const bf16x8*)&Wh[br];
      bl[nt] = *(const bf16x8*)&Wl[br];
    }
    #pragma unroll
    for (int mt = 0; mt < 4; ++mt) {
      int ar = (wm * 64 + mt * 16 + frow) * FPITCH + fk;
      bf16x8 ah = *(const bf16x8*)&Ah[ar];
      bf16x8 al = *(const bf16x8*)&Al[ar];
      #pragma unroll
      for (int nt = 0; nt < 4; ++nt) {
        acc[mt][nt] = __builtin_amdgcn_mfma_f32_16x16x32_bf16(ah, bh[nt], acc[mt][nt], 0, 0, 0);
        acc[mt][nt] = __builtin_amdgcn_mfma_f32_16x16x32_bf16(ah, bl[nt], acc[mt][nt], 0, 0, 0);
        acc[mt][nt] = __builtin_amdgcn_mfma_f32_16x16x32_bf16(al, bh[nt], acc[mt][nt], 0, 0, 0);
      }
    }
  }

  // epilogue: C/D map col=lane&15, row=(lane>>4)*4+reg
  #pragma unroll
  for (int nt = 0; nt < 4; ++nt) {
    int col = n0 + wn * 64 + nt * 16 + frow;
    float bv = bias[col];
    #pragma unroll
    for (int mt = 0; mt < 4; ++mt) {
      int rbase = m0 + wm * 64 + mt * 16 + (lane >> 4) * 4;
      #pragma unroll
      for (int r = 0; r < 4; ++r)
        C[(size_t)(rbase + r) * VOCAB + col] = acc[mt][nt][r] + bv;
    }
  }
}

// ---------------------------------------------------------------------------
extern "C" void kernel_launch(void* const* d_in, const int* in_sizes, int n_in,
                              void* d_out, int out_size, void* d_ws, size_t ws_size,
                              hipStream_t stream)
{
  (void)in_sizes; (void)n_in; (void)out_size; (void)ws_size;
  const int*   x    = (const int*)  d_in[0];
  const float* emb  = (const float*)d_in[1];
  const float* W_ih = (const float*)d_in[2];   // (2, 4096, 1024)
  const float* W_hh = (const float*)d_in[3];
  const float* b_ih = (const float*)d_in[4];   // (2, 4096)
  const float* b_hh = (const float*)d_in[5];
  const float* W_fc = (const float*)d_in[6];   // (32000, 1024)
  const float* b_fc = (const float*)d_in[7];
  float* out = (float*)d_out;                  // scores(512x32000) | h(2x1024) | c(2x1024)

  // workspace layout (floats); ~16.3 MB total
  float* ws    = (float*)d_ws;
  float* G0    = ws;                                         // 512*4096
  float* h0h   = G0   + (size_t)T_STEPS * 4096;              // 513*1024
  float* h1h   = h0h  + (size_t)(T_STEPS + 1) * H_DIM;       // 513*1024
  float* h1out = h1h  + (size_t)(T_STEPS + 1) * H_DIM;       // 512*1024
  int*   xmap  = (int*)(h1out + (size_t)T_STEPS * H_DIM);    // 512 ints
  ushort_t* Ahi = (ushort_t*)(xmap + 512);                   // 512*1024 bf16
  ushort_t* Alo = Ahi + (size_t)T_STEPS * H_DIM;             // 512*1024 bf16

  init_ws_k<<<128, 256, 0, stream>>>(x, h0h, h1h, xmap);

  // G0[t,:] = W_ih0 @ emb[x_t] + b_ih0 + b_hh0   (512 x 4096)
  gemm_atb_k<<<dim3(4096 / BN, T_STEPS / BM), 256, 0, stream>>>(
      nullptr, emb, xmap, W_ih, b_ih, b_hh, G0, T_STEPS, 4096, 1024);

  // sequential scan (two layer domains, sentinel signaling, DPP reduce)
  lstm_seq_k<<<256, 512, 0, stream>>>(
      W_hh, W_ih + (size_t)4096 * 1024, W_hh + (size_t)4096 * 1024,
      b_ih + 4096, b_hh + 4096, G0, h0h, h1h, h1out,
      out + (size_t)T_STEPS * VOCAB);

  // split FC input to bf16 hi/lo
  split_a_k<<<(T_STEPS * H_DIM / 4 + 255) / 256, 256, 0, stream>>>(h1out, Ahi, Alo);

  // scores = outs @ W_fc^T + b_fc  (split-bf16 MFMA)
  fc_mfma_k<<<dim3(VOCAB / FBN, T_STEPS / FBM), 512, 0, stream>>>(
      Ahi, Alo, W_fc, b_fc, out);
}